// Round 1
// 2757.345 us; speedup vs baseline: 2.0274x; 2.0274x over previous
//
#include <hip/hip_runtime.h>

// ---------------- constants ----------------
constexpr int LAYERS = 8;
constexpr int DIM    = 1024;
constexpr int NH     = 16;
constexpr int DK     = 64;
constexpr int FF     = 4096;
constexpr int VOC    = 32000;
constexpr int SEQ    = 1024;
constexpr int BATCH  = 2;
constexpr int MR     = BATCH * SEQ;   // 2048 rows

using bf16x8 = __attribute__((ext_vector_type(8))) short;
using f32x4  = __attribute__((ext_vector_type(4))) float;

static __device__ __forceinline__ short f2bf(float f) {
  unsigned u = __builtin_bit_cast(unsigned, f);
  u += 0x7fffu + ((u >> 16) & 1u);   // round-to-nearest-even
  return (short)(u >> 16);
}

// async global->LDS, 16B per lane; LDS dest must be wave-uniform base (+lane*16)
static __device__ __forceinline__ void gload_lds16(const short* g, short* l) {
  __builtin_amdgcn_global_load_lds(
      (const __attribute__((address_space(1))) unsigned*)g,
      (__attribute__((address_space(3))) unsigned*)l, 16, 0, 0);
}

// ---------------- embedding ----------------
__global__ __launch_bounds__(256) void embed_kernel(
    const int* __restrict__ ids, const float* __restrict__ tok,
    const float* __restrict__ pos, float* __restrict__ x) {
  int row = blockIdx.x;               // b*SEQ + s
  int s   = row & (SEQ - 1);
  int id  = ids[row];
  int c   = threadIdx.x;              // 256 threads x float4 = 1024
  const float4* t4 = (const float4*)(tok + (size_t)id * DIM);
  const float4* p4 = (const float4*)(pos + (size_t)s * DIM);
  float4* x4 = (float4*)(x + (size_t)row * DIM);
  float4 tv = t4[c], pv = p4[c];
  x4[c] = make_float4(tv.x + pv.x, tv.y + pv.y, tv.z + pv.z, tv.w + pv.w);
}

// ---------------- layernorm (fp32 in, bf16 out) ----------------
__global__ __launch_bounds__(256) void ln_kernel(
    const float* __restrict__ x, const float* __restrict__ g,
    const float* __restrict__ b, short* __restrict__ out) {
  int row = blockIdx.x;
  int tid = threadIdx.x;
  const float4* x4 = (const float4*)(x + (size_t)row * DIM);
  float4 v = x4[tid];
  float s = v.x + v.y + v.z + v.w;
  float q = v.x * v.x + v.y * v.y + v.z * v.z + v.w * v.w;
  __shared__ float rs[256], rq[256];
  rs[tid] = s; rq[tid] = q;
  __syncthreads();
  for (int off = 128; off; off >>= 1) {
    if (tid < off) { rs[tid] += rs[tid + off]; rq[tid] += rq[tid + off]; }
    __syncthreads();
  }
  float mean = rs[0] * (1.0f / DIM);
  float var  = rq[0] * (1.0f / DIM) - mean * mean;
  float inv  = rsqrtf(var + 1e-5f);
  float4 gv = ((const float4*)g)[tid];
  float4 bv = ((const float4*)b)[tid];
  int c = tid * 4;
  size_t base = (size_t)row * DIM + c;
  out[base + 0] = f2bf((v.x - mean) * inv * gv.x + bv.x);
  out[base + 1] = f2bf((v.y - mean) * inv * gv.y + bv.y);
  out[base + 2] = f2bf((v.z - mean) * inv * gv.z + bv.z);
  out[base + 3] = f2bf((v.w - mean) * inv * gv.w + bv.w);
}

// ---------------- weight transpose+cast: in [K,N] f32 -> out [N,K] bf16 ----------------
__global__ __launch_bounds__(256) void wt_kernel(
    const float* __restrict__ in, short* __restrict__ out, int K, int N) {
  __shared__ float tile[32][33];
  int nb = blockIdx.x * 32, kb = blockIdx.y * 32;
  size_t zoff = (size_t)blockIdx.z * K * N;
  int tid = threadIdx.x;
  int r = tid >> 3, c4 = (tid & 7) * 4;
  float4 v = *(const float4*)(in + zoff + (size_t)(kb + r) * N + nb + c4);
  tile[r][c4 + 0] = v.x; tile[r][c4 + 1] = v.y;
  tile[r][c4 + 2] = v.z; tile[r][c4 + 3] = v.w;
  __syncthreads();
  short4 o;
  o.x = f2bf(tile[c4 + 0][r]);
  o.y = f2bf(tile[c4 + 1][r]);
  o.z = f2bf(tile[c4 + 2][r]);
  o.w = f2bf(tile[c4 + 3][r]);
  *(short4*)(out + zoff + (size_t)(nb + r) * K + kb + c4) = o;
}

// ---------------- MFMA GEMM: C = A(bf16 [M,K]) @ B^T(bf16 [N,K]) + bias [+resid] [relu] ----
// m97 structure: BM=128, BK=32, global_load_lds(16B) staging, linear LDS, 4 waves.
// BN_=128 -> 2x2 waves, acc 4x4; BN_=64 -> acc 4x2 (for small-N GEMMs, 2x the blocks).
template<int BN_, int OUT_BF16, int RELU, int RESID>
static __device__ __forceinline__ void gemm_body(
    const short* __restrict__ A, const short* __restrict__ Bt,
    const float* __restrict__ bias, const float* resid,
    float* Cf, short* Cb, int Nsz, int Ksz) {
  constexpr int BM = 128, BK = 32;
  constexpr int TJ = BN_ / 32;            // acc tiles per wave in N
  constexpr int BI = BN_ / 64;            // global_load_lds insts for B
  __shared__ __align__(16) short As[BM * BK];
  __shared__ __align__(16) short Bs[BN_ * BK];
  int tid  = threadIdx.x;
  int lane = tid & 63;
  int quad = lane >> 4, l16 = lane & 15;
  int wave = tid >> 6;
  int wm = wave >> 1, wn = wave & 1;
  int mBase = blockIdx.x * BM, nBase = blockIdx.y * BN_;
  int wbase = (tid & ~63) * 8;            // wave-uniform LDS base (shorts)
  int srow = tid >> 2, sk8 = (tid & 3) * 8;
  f32x4 acc[4][TJ] = {};
  for (int k0 = 0; k0 < Ksz; k0 += BK) {
    __syncthreads();
    #pragma unroll
    for (int p = 0; p < 2; ++p)
      gload_lds16(A + (size_t)(mBase + p * 64 + srow) * Ksz + k0 + sk8,
                  As + p * 2048 + wbase);
    #pragma unroll
    for (int p = 0; p < BI; ++p)
      gload_lds16(Bt + (size_t)(nBase + p * 64 + srow) * Ksz + k0 + sk8,
                  Bs + p * 2048 + wbase);
    __syncthreads();   // compiler drains vmcnt(0) before s_barrier
    bf16x8 af[4];
    #pragma unroll
    for (int ti = 0; ti < 4; ++ti)
      af[ti] = *(const bf16x8*)(As + (wm * 64 + ti * 16 + l16) * BK + quad * 8);
    #pragma unroll
    for (int tj = 0; tj < TJ; ++tj) {
      bf16x8 bfr = *(const bf16x8*)(Bs + (wn * (BN_ / 2) + tj * 16 + l16) * BK + quad * 8);
      #pragma unroll
      for (int ti = 0; ti < 4; ++ti)
        acc[ti][tj] = __builtin_amdgcn_mfma_f32_16x16x32_bf16(af[ti], bfr, acc[ti][tj], 0, 0, 0);
    }
  }
  // epilogue
  #pragma unroll
  for (int tj = 0; tj < TJ; ++tj) {
    int col = nBase + wn * (BN_ / 2) + tj * 16 + l16;
    float bv = bias[col];
    #pragma unroll
    for (int ti = 0; ti < 4; ++ti) {
      #pragma unroll
      for (int r = 0; r < 4; ++r) {
        int row = mBase + wm * 64 + ti * 16 + quad * 4 + r;
        float val = acc[ti][tj][r] + bv;
        if (RESID) val += resid[(size_t)row * Nsz + col];
        if (RELU)  val = fmaxf(val, 0.0f);
        if (OUT_BF16) Cb[(size_t)row * Nsz + col] = f2bf(val);
        else          Cf[(size_t)row * Nsz + col] = val;
      }
    }
  }
}

template<int BN_, int OUT_BF16, int RELU, int RESID>
__global__ __launch_bounds__(256) void gemm_kernel(
    const short* A, const short* Bt, const float* bias, const float* resid,
    float* Cf, short* Cb, int Nsz, int Ksz) {
  gemm_body<BN_, OUT_BF16, RELU, RESID>(A, Bt, bias, resid, Cf, Cb, Nsz, Ksz);
}

__global__ __launch_bounds__(256) void gemm_qkv_kernel(
    const short* A, const short* Wqt, const short* Wkt, const short* Wvt,
    const float* b0, const float* b1, const float* b2,
    short* o0, short* o1, short* o2, int Nsz, int Ksz) {
  int z = blockIdx.z;
  const short* Bt   = (z == 0) ? Wqt : (z == 1) ? Wkt : Wvt;
  const float* bias = (z == 0) ? b0 : (z == 1) ? b1 : b2;
  short* Cb         = (z == 0) ? o0 : (z == 1) ? o1 : o2;
  gemm_body<64, 1, 0, 0>(A, Bt, bias, nullptr, nullptr, Cb, Nsz, Ksz);
}

// ---------------- flash attention (bf16 in/out, MFMA, online softmax) ----------------
// grid: (SEQ/16, NH, BATCH), block: 64 (1 wave). One wave handles 16 queries.
__global__ __launch_bounds__(64) void attn_kernel(
    const short* __restrict__ q, const short* __restrict__ k,
    const short* __restrict__ v, short* __restrict__ out) {
  int qt = blockIdx.x, h = blockIdx.y, b = blockIdx.z;
  int lane = threadIdx.x;
  int quad = lane >> 4, l16 = lane & 15;
  int qbase = qt * 16;
  const size_t baseRow = (size_t)b * SEQ;
  const float scale = 0.125f;  // 1/sqrt(64)

  // Q fragments: A-layout, lane holds Q[m=l16][d=c*32+quad*8+j] — direct bf16 vector loads
  bf16x8 qf[2];
  {
    int qrow = qbase + l16;
    const short* qp = q + (baseRow + qrow) * DIM + h * DK;
    #pragma unroll
    for (int c = 0; c < 2; ++c)
      qf[c] = *(const bf16x8*)(qp + c * 32 + quad * 8);
  }

  f32x4 o_acc[4] = {};
  float Mr[4], Lr[4];
  #pragma unroll
  for (int r = 0; r < 4; ++r) { Mr[r] = -1e30f; Lr[r] = 0.0f; }
  __shared__ __align__(16) short Ps[16 * 32];

  int nkt = qbase / 32 + 1;  // causal: key tiles of 32 covering keys <= qbase+15
  for (int kt = 0; kt < nkt; ++kt) {
    // --- scores: two 16x16 tiles (t=0,1), K-dim = 64 via 2 mfma each ---
    f32x4 sc[2];
    #pragma unroll
    for (int t = 0; t < 2; ++t) {
      int krow = kt * 32 + t * 16 + l16;
      const short* kp = k + (baseRow + krow) * DIM + h * DK;
      f32x4 s = {};
      #pragma unroll
      for (int c = 0; c < 2; ++c) {
        bf16x8 kf = *(const bf16x8*)(kp + c * 32 + quad * 8);
        s = __builtin_amdgcn_mfma_f32_16x16x32_bf16(qf[c], kf, s, 0, 0, 0);
      }
      int kcol = kt * 32 + t * 16 + l16;
      #pragma unroll
      for (int r = 0; r < 4; ++r) {
        int qrow = qbase + quad * 4 + r;
        sc[t][r] = (kcol > qrow) ? -1e9f : s[r] * scale;
      }
    }
    // --- online softmax (rows quad*4+r, reduce over 16-lane col groups) ---
    float tm[4], alpha[4], p[2][4], rowsum[4];
    #pragma unroll
    for (int r = 0; r < 4; ++r) tm[r] = fmaxf(sc[0][r], sc[1][r]);
    #pragma unroll
    for (int off = 1; off < 16; off <<= 1) {
      #pragma unroll
      for (int r = 0; r < 4; ++r) tm[r] = fmaxf(tm[r], __shfl_xor(tm[r], off, 64));
    }
    #pragma unroll
    for (int r = 0; r < 4; ++r) {
      float mnew = fmaxf(Mr[r], tm[r]);
      alpha[r] = __expf(Mr[r] - mnew);
      Mr[r] = mnew;
      float p0 = __expf(sc[0][r] - mnew);
      float p1 = __expf(sc[1][r] - mnew);
      p[0][r] = p0; p[1][r] = p1;
      rowsum[r] = p0 + p1;
    }
    #pragma unroll
    for (int off = 1; off < 16; off <<= 1) {
      #pragma unroll
      for (int r = 0; r < 4; ++r) rowsum[r] += __shfl_xor(rowsum[r], off, 64);
    }
    #pragma unroll
    for (int r = 0; r < 4; ++r) Lr[r] = Lr[r] * alpha[r] + rowsum[r];
    #pragma unroll
    for (int n = 0; n < 4; ++n) {
      f32x4 t = o_acc[n];
      #pragma unroll
      for (int r = 0; r < 4; ++r) t[r] *= alpha[r];
      o_acc[n] = t;
    }
    // --- P: C-layout -> A-layout via LDS ---
    __syncthreads();
    #pragma unroll
    for (int t = 0; t < 2; ++t)
      #pragma unroll
      for (int r = 0; r < 4; ++r)
        Ps[(quad * 4 + r) * 32 + t * 16 + l16] = f2bf(p[t][r]);
    __syncthreads();
    bf16x8 pf = *(const bf16x8*)(Ps + l16 * 32 + quad * 8);
    // --- PV: B-frag = V[key=quad*8+j][d=n*16+l16] ---
    #pragma unroll
    for (int n = 0; n < 4; ++n) {
      bf16x8 vf;
      #pragma unroll
      for (int j = 0; j < 8; ++j) {
        int vrow = kt * 32 + quad * 8 + j;
        vf[j] = v[(baseRow + vrow) * DIM + h * DK + n * 16 + l16];
      }
      o_acc[n] = __builtin_amdgcn_mfma_f32_16x16x32_bf16(pf, vf, o_acc[n], 0, 0, 0);
    }
  }
  // --- write (bf16 for Wo GEMM A-operand) ---
  #pragma unroll
  for (int n = 0; n < 4; ++n) {
    #pragma unroll
    for (int r = 0; r < 4; ++r) {
      int qrow = qbase + quad * 4 + r;
      out[(baseRow + qrow) * DIM + h * DK + n * 16 + l16] = f2bf(o_acc[n][r] / Lr[r]);
    }
  }
}

// ---------------- launch ----------------
extern "C" void kernel_launch(void* const* d_in, const int* in_sizes, int n_in,
                              void* d_out, int out_size, void* d_ws, size_t ws_size,
                              hipStream_t stream) {
  (void)in_sizes; (void)n_in; (void)out_size;
  const int*   ids  = (const int*)d_in[0];
  const float* tok  = (const float*)d_in[1];
  const float* pos  = (const float*)d_in[2];
  const float* Wq   = (const float*)d_in[3];
  const float* bq   = (const float*)d_in[4];
  const float* Wk   = (const float*)d_in[5];
  const float* bk   = (const float*)d_in[6];
  const float* Wv   = (const float*)d_in[7];
  const float* bv   = (const float*)d_in[8];
  const float* Wo   = (const float*)d_in[9];
  const float* bo   = (const float*)d_in[10];
  const float* W1   = (const float*)d_in[11];
  const float* b1   = (const float*)d_in[12];
  const float* W2   = (const float*)d_in[13];
  const float* b2   = (const float*)d_in[14];
  const float* g1   = (const float*)d_in[15];
  const float* be1  = (const float*)d_in[16];
  const float* g2   = (const float*)d_in[17];
  const float* be2  = (const float*)d_in[18];
  const float* gf   = (const float*)d_in[19];
  const float* bfl  = (const float*)d_in[20];
  const float* Wout = (const float*)d_in[21];
  const float* bout = (const float*)d_in[22];
  float* outp = (float*)d_out;

  char* p = (char*)d_ws;
  auto alloc = [&](size_t bytes) {
    char* r = p; p += (bytes + 255) & ~(size_t)255; return r;
  };
  float* x    = (float*)alloc((size_t)MR * DIM * 4);   // residual stream
  short* hb   = (short*)alloc((size_t)MR * DIM * 2);   // LN output bf16
  short* qb   = (short*)alloc((size_t)MR * DIM * 2);   // Q bf16
  short* kbuf = (short*)alloc((size_t)MR * DIM * 2);   // K bf16
  short* vbuf = (short*)alloc((size_t)MR * DIM * 2);   // V bf16
  short* aob  = (short*)alloc((size_t)MR * DIM * 2);   // attn out bf16
  short* ffb  = (short*)alloc((size_t)MR * FF * 2);    // ffn1 out bf16
  short* wtout = (short*)alloc((size_t)DIM * VOC * 2); // Wout^T bf16 [V,D]

  const size_t dd = (size_t)DIM * DIM, df = (size_t)DIM * FF;
  size_t fullNeed = (size_t)(p - (char*)d_ws) +
                    ((4 * dd + 2 * df) * LAYERS) * 2 + 8 * 256;
  bool full = ws_size >= fullNeed;
  short *wtq, *wtk, *wtv, *wto, *wt1, *wt2;
  if (full) {   // all layers pre-converted up front
    wtq = (short*)alloc(dd * LAYERS * 2);
    wtk = (short*)alloc(dd * LAYERS * 2);
    wtv = (short*)alloc(dd * LAYERS * 2);
    wto = (short*)alloc(dd * LAYERS * 2);
    wt1 = (short*)alloc(df * LAYERS * 2);
    wt2 = (short*)alloc(df * LAYERS * 2);
  } else {      // rotating per-layer buffers
    wtq = (short*)alloc(dd * 2);
    wtk = (short*)alloc(dd * 2);
    wtv = (short*)alloc(dd * 2);
    wto = (short*)alloc(dd * 2);
    wt1 = (short*)alloc(df * 2);
    wt2 = (short*)alloc(df * 2);
  }

  // weight convert+transpose (once per launch)
  wt_kernel<<<dim3(VOC / 32, DIM / 32, 1), 256, 0, stream>>>(Wout, wtout, DIM, VOC);
  if (full) {
    wt_kernel<<<dim3(DIM / 32, DIM / 32, LAYERS), 256, 0, stream>>>(Wq, wtq, DIM, DIM);
    wt_kernel<<<dim3(DIM / 32, DIM / 32, LAYERS), 256, 0, stream>>>(Wk, wtk, DIM, DIM);
    wt_kernel<<<dim3(DIM / 32, DIM / 32, LAYERS), 256, 0, stream>>>(Wv, wtv, DIM, DIM);
    wt_kernel<<<dim3(DIM / 32, DIM / 32, LAYERS), 256, 0, stream>>>(Wo, wto, DIM, DIM);
    wt_kernel<<<dim3(FF / 32, DIM / 32, LAYERS), 256, 0, stream>>>(W1, wt1, DIM, FF);
    wt_kernel<<<dim3(DIM / 32, FF / 32, LAYERS), 256, 0, stream>>>(W2, wt2, FF, DIM);
  }

  embed_kernel<<<MR, 256, 0, stream>>>(ids, tok, pos, x);

  for (int l = 0; l < LAYERS; ++l) {
    const short* lwq = wtq + (full ? l * dd : 0);
    const short* lwk = wtk + (full ? l * dd : 0);
    const short* lwv = wtv + (full ? l * dd : 0);
    const short* lwo = wto + (full ? l * dd : 0);
    const short* lw1 = wt1 + (full ? l * df : 0);
    const short* lw2 = wt2 + (full ? l * df : 0);
    if (!full) {
      wt_kernel<<<dim3(DIM / 32, DIM / 32, 1), 256, 0, stream>>>(Wq + l * dd, wtq, DIM, DIM);
      wt_kernel<<<dim3(DIM / 32, DIM / 32, 1), 256, 0, stream>>>(Wk + l * dd, wtk, DIM, DIM);
      wt_kernel<<<dim3(DIM / 32, DIM / 32, 1), 256, 0, stream>>>(Wv + l * dd, wtv, DIM, DIM);
      wt_kernel<<<dim3(DIM / 32, DIM / 32, 1), 256, 0, stream>>>(Wo + l * dd, wto, DIM, DIM);
      wt_kernel<<<dim3(FF / 32, DIM / 32, 1), 256, 0, stream>>>(W1 + l * df, wt1, DIM, FF);
      wt_kernel<<<dim3(DIM / 32, FF / 32, 1), 256, 0, stream>>>(W2 + l * df, wt2, FF, DIM);
    }
    ln_kernel<<<MR, 256, 0, stream>>>(x, g1 + l * DIM, be1 + l * DIM, hb);
    gemm_qkv_kernel<<<dim3(MR / 128, DIM / 64, 3), 256, 0, stream>>>(
        hb, lwq, lwk, lwv, bq + l * DIM, bk + l * DIM, bv + l * DIM,
        qb, kbuf, vbuf, DIM, DIM);
    attn_kernel<<<dim3(SEQ / 16, NH, BATCH), 64, 0, stream>>>(qb, kbuf, vbuf, aob);
    gemm_kernel<64, 0, 0, 1><<<dim3(MR / 128, DIM / 64), 256, 0, stream>>>(
        aob, lwo, bo + l * DIM, x, x, nullptr, DIM, DIM);
    ln_kernel<<<MR, 256, 0, stream>>>(x, g2 + l * DIM, be2 + l * DIM, hb);
    gemm_kernel<128, 1, 1, 0><<<dim3(MR / 128, FF / 128), 256, 0, stream>>>(
        hb, lw1, b1 + l * FF, nullptr, nullptr, ffb, FF, DIM);
    gemm_kernel<64, 0, 0, 1><<<dim3(MR / 128, DIM / 64), 256, 0, stream>>>(
        ffb, lw2, b2 + l * DIM, x, x, nullptr, DIM, FF);
  }

  ln_kernel<<<MR, 256, 0, stream>>>(x, gf, bfl, hb);
  gemm_kernel<128, 0, 0, 0><<<dim3(MR / 128, VOC / 128), 256, 0, stream>>>(
      hb, wtout, bout, nullptr, outp, nullptr, VOC, DIM);
}